// Round 14
// baseline (11819.777 us; speedup 1.0000x reference)
//
#include <hip/hip_runtime.h>
#include <hip/hip_bf16.h>

typedef __attribute__((ext_vector_type(8))) short short8;
typedef __attribute__((ext_vector_type(4))) float f32x4;
typedef __attribute__((ext_vector_type(4))) unsigned u32x4;

#define T_STEPS 2048
#define HDIM 512
#define SLICE_T (64 * 512)      // elems per time slice
#define NGROUP 8                // batch groups (8 rows each)
#define NSLICE 16               // col slices (32 cols each)
#define CAN_OFF 0               // canaries: [128] 128B lines (16 KB)
#define COLSUM_OFF  16384       // colsum  f32[512]
#define COLSUM1_OFF 18432       // colsum1 f32[512] (h0-weighted)
#define AFLAG_OFF   20480       // allflagg u32[8]
#define CERT_OFF    20608       // cert u32[8]
#define RING_OFF 131072         // ring [2][64][512] packed u32 (256 KB)
#define SPIN_CAP 200000         // bounded spin; dead-mode, no hang
#define SAT_MARGIN 10.0f        // > both tanh==1.0f cutoffs (9.01 / 8.7) + skew

#define MFMA16 __builtin_amdgcn_mfma_f32_16x16x32_bf16
#define ALOAD(p)   __hip_atomic_load((p), __ATOMIC_RELAXED, __HIP_MEMORY_SCOPE_AGENT)
#define ASWAP(p,v) (void)__hip_atomic_exchange((p), (v), __ATOMIC_RELAXED, __HIP_MEMORY_SCOPE_AGENT)

static __device__ __forceinline__ short f2bf(float f) {
    __hip_bfloat16 h = __float2bfloat16(f);
    return __builtin_bit_cast(short, h);
}
static __device__ __forceinline__ float bf2f(short s) {
    unsigned u = ((unsigned)(unsigned short)s) << 16;
    return __builtin_bit_cast(float, u);
}
static __device__ __forceinline__ unsigned packsplit(float f) {
    short hi = f2bf(f);
    short lo = f2bf(f - bf2f(hi));
    return (unsigned)(unsigned short)hi | ((unsigned)(unsigned short)lo << 16);
}
static __device__ __forceinline__ void unpack2w(unsigned p0, unsigned p1,
                                                unsigned& hw, unsigned& lw) {
    hw = __builtin_amdgcn_perm(p1, p0, 0x05040100u);
    lw = __builtin_amdgcn_perm(p1, p0, 0x07060302u);
}
union S8U { short8 s8; unsigned u[4]; };
static __device__ __forceinline__ void build8v(u32x4 a, u32x4 b, short8& hi, short8& lo) {
    S8U H, L;
    unpack2w(a[0], a[1], H.u[0], L.u[0]);
    unpack2w(a[2], a[3], H.u[1], L.u[1]);
    unpack2w(b[0], b[1], H.u[2], L.u[2]);
    unpack2w(b[2], b[3], H.u[3], L.u[3]);
    hi = H.s8; lo = L.s8;
}
static __device__ __forceinline__ void split8v(f32x4 u, f32x4 v, short8& hi, short8& lo) {
#pragma unroll
    for (int j = 0; j < 4; ++j) { short h = f2bf(u[j]); hi[j] = h; lo[j] = f2bf(u[j] - bf2f(h)); }
#pragma unroll
    for (int j = 0; j < 4; ++j) { short h = f2bf(v[j]); hi[4+j] = h; lo[4+j] = f2bf(v[j] - bf2f(h)); }
}
static __device__ __forceinline__ float fast_tanh(float x) {
    const float xc = fminf(15.0f, fmaxf(-15.0f, x));
    const float e = __expf(2.0f * xc);
    return (e - 1.0f) / (e + 1.0f);
}

// ------- Phase 0: colsum, colsum1 (= h0@Wh per col), init allflagg --------
__global__ __launch_bounds__(512, 1) void rnn_colsum(
    const float* __restrict__ weight, const float* __restrict__ init_h,
    float* __restrict__ colsum, float* __restrict__ colsum1,
    unsigned* __restrict__ allflagg)
{
    const int c = threadIdx.x;
    float s = 0.f, s1 = 0.f;
    for (int k = 0; k < HDIM; ++k) {
        const float w = weight[(size_t)(HDIM + k) * HDIM + c];
        s += w; s1 += init_h[k] * w;
    }
    colsum[c] = s; colsum1[c] = s1;
    if (c < NGROUP) allflagg[c] = 1u;
}

// ------- Phase 1: xp(t) = input[t] @ Wx + bias -> out[t+1] (proven) -------
__global__ __launch_bounds__(256, 2) void rnn_xproj(
    const float* __restrict__ input, const float* __restrict__ weight,
    const float* __restrict__ bias, float* __restrict__ out)
{
    __shared__ unsigned alds[64 * 128];
    __shared__ unsigned wlds[64 * 128];
    const int tid = threadIdx.x, lane = tid & 63, wv = tid >> 6;
    const int t = blockIdx.x >> 3, ct = blockIdx.x & 7;
    const int r16 = lane & 15, kg = lane >> 4, koff = kg * 8;
    const int colt = wv * 16 + r16;
    const int gcol = ct * 64 + colt;
    const float bv = bias[gcol];

    f32x4 acc[4][3];
#pragma unroll
    for (int mt = 0; mt < 4; ++mt) {
        acc[mt][0] = (f32x4){bv, bv, bv, bv};
        acc[mt][1] = (f32x4){0, 0, 0, 0};
        acc[mt][2] = (f32x4){0, 0, 0, 0};
    }
    for (int kq = 0; kq < 4; ++kq) {
        __syncthreads();
        for (int f = tid; f < 64 * 32; f += 256) {
            const int row = f >> 5, sg = f & 31;
            f32x4 v = *(const f32x4*)(input + (size_t)t * SLICE_T + row * HDIM + kq * 128 + sg * 4);
            const unsigned idx = ((unsigned)(row * 128 + sg * 4)) ^ (((unsigned)(row & 7)) << 2);
            u32x4 pk = {packsplit(v[0]), packsplit(v[1]), packsplit(v[2]), packsplit(v[3])};
            *(u32x4*)(&alds[idx]) = pk;
        }
        for (int f = tid; f < 128 * 16; f += 256) {
            const int k = f >> 4, cs = f & 15;
            f32x4 v = *(const f32x4*)(weight + (size_t)(kq * 128 + k) * HDIM + ct * 64 + cs * 4);
#pragma unroll
            for (int j = 0; j < 4; ++j) {
                const int c = cs * 4 + j;
                wlds[((unsigned)(c * 128 + k)) ^ (((unsigned)(c & 7)) << 2)] = packsplit(v[j]);
            }
        }
        __syncthreads();
#pragma unroll
        for (int c2 = 0; c2 < 4; ++c2) {
            const int kp = c2 * 32 + koff;
            const unsigned bi = (unsigned)(colt * 128 + kp), bx = ((unsigned)(colt & 7)) << 2;
            u32x4 qb0 = *(const u32x4*)&wlds[bi ^ bx];
            u32x4 qb1 = *(const u32x4*)&wlds[(bi + 4) ^ bx];
            short8 bhi, blo; build8v(qb0, qb1, bhi, blo);
#pragma unroll
            for (int mt = 0; mt < 4; ++mt) {
                const int row = mt * 16 + r16;
                const unsigned ai = (unsigned)(row * 128 + kp), ax = ((unsigned)(row & 7)) << 2;
                u32x4 qa0 = *(const u32x4*)&alds[ai ^ ax];
                u32x4 qa1 = *(const u32x4*)&alds[(ai + 4) ^ ax];
                short8 ahi, alo; build8v(qa0, qa1, ahi, alo);
                acc[mt][0] = MFMA16(ahi, bhi, acc[mt][0], 0, 0, 0);
                acc[mt][1] = MFMA16(alo, bhi, acc[mt][1], 0, 0, 0);
                acc[mt][2] = MFMA16(ahi, blo, acc[mt][2], 0, 0, 0);
            }
        }
    }
    float* ob = out + (size_t)(t + 1) * SLICE_T;
#pragma unroll
    for (int mt = 0; mt < 4; ++mt)
#pragma unroll
        for (int r = 0; r < 4; ++r)
            ob[(mt * 16 + kg * 4 + r) * HDIM + gcol] =
                acc[mt][0][r] + acc[mt][1][r] + acc[mt][2][r];
}

// ------- Phase 1b: allflagg[g] &= AND_{t>=3} [min(xp_t + colsum) > 10] -----
// (h_t == 1 for t>=3 is certified separately; these flags extend it to 2048)
__global__ __launch_bounds__(256, 2) void rnn_flags(
    const float* __restrict__ out, const float* __restrict__ colsum,
    unsigned* __restrict__ allflagg)
{
    __shared__ float cs[HDIM];
    __shared__ int ok[8];
    const int tid = threadIdx.x, t = blockIdx.x;
    if (t < 3) return;   // h4..h2048 need t = 3..2047
    for (int i = tid; i < HDIM; i += 256) cs[i] = colsum[i];
    if (tid < 8) ok[tid] = 1;
    __syncthreads();
    const float* xp = out + (size_t)(t + 1) * SLICE_T;
    for (int i = tid; i < SLICE_T; i += 256)
        if (xp[i] + cs[i & 511] <= SAT_MARGIN) ok[i >> 12] = 0;
    __syncthreads();
    if (tid < 8 && !ok[tid]) atomicAnd(&allflagg[tid], 0u);
}

// ------- Phase 1c: per-group certificate for h3 == exactly +1 -------------
// h1 = tanh(xp0 + colsum1); h2 = tanh(xp1 + h1@Wh); m3 = min(xp2 + h2@Wh).
// cert[g] = (m3 > 10) && allflagg[g]. R12/R13 showed min(preact2) straddles
// ~9.5-10 (2/8 groups pass) while h2's deficits are O(1e-5) -> min(preact3)
// ~ 18: certifying ONE STEP LATER moves the margin from 0 to ~8.
// Skews (scan-bf16 h2 vs this f32 h2; ref f32 vs this) << margin 1 over the
// 9.01 tanhf==1.0f cutoff => h_t == exactly 1.0f for ALL t>=3, both ariths.
__global__ __launch_bounds__(256, 1) void rnn_cert(
    const float* __restrict__ weight, const float* __restrict__ out,
    const float* __restrict__ colsum1, const unsigned* __restrict__ allflagg,
    unsigned* __restrict__ cert)
{
    __shared__ float h1[8][HDIM];
    __shared__ float h2[8][HDIM];
    __shared__ float mins[256];
    const int g = blockIdx.x, tid = threadIdx.x;
    for (int i = tid; i < 8 * HDIM; i += 256) {
        const int b = i >> 9, c = i & 511;
        h1[b][c] = tanhf(out[(size_t)1 * SLICE_T + (size_t)(g * 8 + b) * HDIM + c] + colsum1[c]);
    }
    __syncthreads();
    for (int c = tid; c < HDIM; c += 256) {        // h2 = tanh(xp1 + h1@Wh)
        float acc[8] = {0, 0, 0, 0, 0, 0, 0, 0};
        for (int k = 0; k < HDIM; ++k) {
            const float w = weight[(size_t)(HDIM + k) * HDIM + c];
#pragma unroll
            for (int b = 0; b < 8; ++b) acc[b] += h1[b][k] * w;
        }
#pragma unroll
        for (int b = 0; b < 8; ++b)
            h2[b][c] = tanhf(out[(size_t)2 * SLICE_T + (size_t)(g * 8 + b) * HDIM + c] + acc[b]);
    }
    __syncthreads();
    float mn = 1e30f;
    for (int c = tid; c < HDIM; c += 256) {        // m3 = min(xp2 + h2@Wh)
        float acc[8] = {0, 0, 0, 0, 0, 0, 0, 0};
        for (int k = 0; k < HDIM; ++k) {
            const float w = weight[(size_t)(HDIM + k) * HDIM + c];
#pragma unroll
            for (int b = 0; b < 8; ++b) acc[b] += h2[b][k] * w;
        }
#pragma unroll
        for (int b = 0; b < 8; ++b)
            mn = fminf(mn, out[(size_t)3 * SLICE_T + (size_t)(g * 8 + b) * HDIM + c] + acc[b]);
    }
    mins[tid] = mn; __syncthreads();
    for (int w = 128; w > 0; w >>= 1) {
        if (tid < w) mins[tid] = fminf(mins[tid], mins[tid + w]);
        __syncthreads();
    }
    if (tid == 0) cert[g] = (mins[0] > SAT_MARGIN && allflagg[g] != 0u) ? 1u : 0u;
}

// ------- Phase 2: scan. ALL groups: protocol t=0..2 (out[1..3]); cert
// groups then blast out[4..2048] = 1.0 and exit. Uncert: full R6 protocol.
__global__ __launch_bounds__(128, 1) void rnn_scan(
    const float* __restrict__ weight, const float* __restrict__ init_h,
    float* __restrict__ out, unsigned char* __restrict__ ws,
    const unsigned* __restrict__ cert)
{
    __shared__ u32x4 whfA[16][2][64];
    __shared__ u32x4 whfB[16][2][64];
    unsigned* canary = (unsigned*)(ws + CAN_OFF);
    unsigned* ring   = (unsigned*)(ws + RING_OFF);

    const int tid = threadIdx.x, lane = tid & 63, wv = tid >> 6;
    const int g = blockIdx.x & 7, s = blockIdx.x >> 3;
    const int r16 = lane & 15, kg = lane >> 4, koff = kg * 8;
    const int gcol = s * 32 + wv * 16 + r16;
    const int brow = g * 8 + (r16 & 7);
    const bool certg = cert[g] != 0u;

    // one-time: Wh column-slice B-fragments into LDS
#pragma unroll
    for (int c = 0; c < 16; ++c) {
        unsigned p[8];
#pragma unroll
        for (int j = 0; j < 8; ++j)
            p[j] = packsplit(weight[(size_t)(HDIM + c * 32 + koff + j) * HDIM + gcol]);
        whfA[c][wv][lane] = (u32x4){p[0], p[1], p[2], p[3]};
        whfB[c][wv][lane] = (u32x4){p[4], p[5], p[6], p[7]};
    }
    for (int f = tid; f < 8 * 32; f += 128) {
        const int rr = f >> 5, cc = f & 31;
        out[(size_t)(g * 8 + rr) * HDIM + s * 32 + cc] = init_h[s * 32 + cc];
    }
    __syncthreads();

    // ---- t = 0: local compute from init_h; post unconditionally ----
    {
        const float* xpp = out + (size_t)1 * SLICE_T
                               + (size_t)(g * 8 + (kg & 1) * 4) * HDIM + gcol;
        const float xp0 = xpp[0 * HDIM], xp1 = xpp[1 * HDIM];
        const float xp2 = xpp[2 * HDIM], xp3 = xpp[3 * HDIM];
        f32x4 aA = {0, 0, 0, 0}, aB = {0, 0, 0, 0}, aC = {0, 0, 0, 0};
#pragma unroll
        for (int c = 0; c < 16; ++c) {
            f32x4 u = *(const f32x4*)(init_h + c * 32 + koff);
            f32x4 v = *(const f32x4*)(init_h + c * 32 + koff + 4);
            short8 ahi, alo; split8v(u, v, ahi, alo);
            short8 bhi, blo; build8v(whfA[c][wv][lane], whfB[c][wv][lane], bhi, blo);
            aA = MFMA16(ahi, bhi, aA, 0, 0, 0);
            aB = MFMA16(alo, bhi, aB, 0, 0, 0);
            aC = MFMA16(ahi, blo, aC, 0, 0, 0);
        }
        const float hn0 = fast_tanh(aA[0] + aB[0] + aC[0] + xp0);
        const float hn1 = fast_tanh(aA[1] + aB[1] + aC[1] + xp1);
        const float hn2 = fast_tanh(aA[2] + aB[2] + aC[2] + xp2);
        const float hn3 = fast_tanh(aA[3] + aB[3] + aC[3] + xp3);
        if (kg < 2) {
            unsigned* wsl = ring + 1 * SLICE_T + (size_t)(g * 8 + kg * 4) * HDIM + gcol;
            ASWAP(&wsl[0 * HDIM], packsplit(hn0));
            ASWAP(&wsl[1 * HDIM], packsplit(hn1));
            ASWAP(&wsl[2 * HDIM], packsplit(hn2));
            ASWAP(&wsl[3 * HDIM], packsplit(hn3));
        }
        asm volatile("s_waitcnt vmcnt(0)" ::: "memory");
        __syncthreads();
        if (tid == 0) ASWAP(&canary[(g * NSLICE + s) * 32], 1u);
        if (kg < 2) {
            float* op = out + (size_t)1 * SLICE_T + (size_t)(g * 8 + kg * 4) * HDIM + gcol;
            __builtin_nontemporal_store(hn0, op + 0 * HDIM);
            __builtin_nontemporal_store(hn1, op + 1 * HDIM);
            __builtin_nontemporal_store(hn2, op + 2 * HDIM);
            __builtin_nontemporal_store(hn3, op + 3 * HDIM);
        }
    }

    // ---- t = 1..: protocol; cert groups exit to the ones-blast at t==3 ----
    for (int t = 1; t < T_STEPS; ++t) {
        if (certg && t == 3) {
            // out[4..2048] == exactly 1.0 — pure NT streams, no protocol
            const int idx = tid & 63, row = idx >> 3, c4 = idx & 7;
            const f32x4 ones = {1.f, 1.f, 1.f, 1.f};
            float* base = out + (size_t)(g * 8 + row) * HDIM + s * 32 + c4 * 4;
            for (int t2 = 4 + (tid >> 6); t2 <= T_STEPS; t2 += 2)
                __builtin_nontemporal_store(ones, (f32x4*)(base + (size_t)t2 * SLICE_T));
            return;
        }

        const bool has_next = (t + 1 < T_STEPS);
        const float* xpp = out + (size_t)(t + 1) * SLICE_T
                               + (size_t)(g * 8 + (kg & 1) * 4) * HDIM + gcol;
        const float xp0 = xpp[0 * HDIM], xp1 = xpp[1 * HDIM];
        const float xp2 = xpp[2 * HDIM], xp3 = xpp[3 * HDIM];

        int to = 0;
        if (wv == 0) {
            unsigned it = 0;
            for (;;) {
                unsigned cv = 0xffffffffu;
                if (lane < NSLICE) cv = ALOAD(&canary[(g * NSLICE + lane) * 32]);
                if (__all((int)(cv >= (unsigned)t))) break;
                if (++it > SPIN_CAP) { to = 1; break; }
            }
        }
        if (__syncthreads_count(to)) return;   // hang-proof abort

        const unsigned* rb = ring + (t & 1) * SLICE_T + brow * HDIM;
        f32x4 aA = {0, 0, 0, 0}, aB = {0, 0, 0, 0}, aC = {0, 0, 0, 0};
#pragma unroll
        for (int c = 0; c < 16; ++c) {
            const unsigned* p = rb + c * 32 + koff;
            unsigned long long q0 = ALOAD((const unsigned long long*)(p + 0));
            unsigned long long q1 = ALOAD((const unsigned long long*)(p + 2));
            unsigned long long q2 = ALOAD((const unsigned long long*)(p + 4));
            unsigned long long q3 = ALOAD((const unsigned long long*)(p + 6));
            S8U hh, hl;
            unpack2w((unsigned)q0, (unsigned)(q0 >> 32), hh.u[0], hl.u[0]);
            unpack2w((unsigned)q1, (unsigned)(q1 >> 32), hh.u[1], hl.u[1]);
            unpack2w((unsigned)q2, (unsigned)(q2 >> 32), hh.u[2], hl.u[2]);
            unpack2w((unsigned)q3, (unsigned)(q3 >> 32), hh.u[3], hl.u[3]);
            short8 bhi, blo; build8v(whfA[c][wv][lane], whfB[c][wv][lane], bhi, blo);
            aA = MFMA16(hh.s8, bhi, aA, 0, 0, 0);
            aB = MFMA16(hl.s8, bhi, aB, 0, 0, 0);
            aC = MFMA16(hh.s8, blo, aC, 0, 0, 0);
        }

        const float hn0 = fast_tanh(aA[0] + aB[0] + aC[0] + xp0);
        const float hn1 = fast_tanh(aA[1] + aB[1] + aC[1] + xp1);
        const float hn2 = fast_tanh(aA[2] + aB[2] + aC[2] + xp2);
        const float hn3 = fast_tanh(aA[3] + aB[3] + aC[3] + xp3);

        if (kg < 2 && has_next) {
            unsigned* wsl = ring + ((t + 1) & 1) * SLICE_T
                                 + (size_t)(g * 8 + kg * 4) * HDIM + gcol;
            ASWAP(&wsl[0 * HDIM], packsplit(hn0));
            ASWAP(&wsl[1 * HDIM], packsplit(hn1));
            ASWAP(&wsl[2 * HDIM], packsplit(hn2));
            ASWAP(&wsl[3 * HDIM], packsplit(hn3));
        }
        asm volatile("s_waitcnt vmcnt(0)" ::: "memory");
        __syncthreads();
        if (tid == 0 && has_next)
            ASWAP(&canary[(g * NSLICE + s) * 32], (unsigned)(t + 1));

        if (kg < 2) {
            float* op = out + (size_t)(t + 1) * SLICE_T
                            + (size_t)(g * 8 + kg * 4) * HDIM + gcol;
            __builtin_nontemporal_store(hn0, op + 0 * HDIM);
            __builtin_nontemporal_store(hn1, op + 1 * HDIM);
            __builtin_nontemporal_store(hn2, op + 2 * HDIM);
            __builtin_nontemporal_store(hn3, op + 3 * HDIM);
        }
    }
}

extern "C" void kernel_launch(void* const* d_in, const int* in_sizes, int n_in,
                              void* d_out, int out_size, void* d_ws, size_t ws_size,
                              hipStream_t stream) {
    const float* input  = (const float*)d_in[0];
    const float* weight = (const float*)d_in[1];
    const float* biasp  = (const float*)d_in[2];
    const float* inith  = (const float*)d_in[3];
    float* out = (float*)d_out;
    unsigned char* ws = (unsigned char*)d_ws;

    // re-zero canaries each call; everything else rewritten per call.
    hipMemsetAsync(d_ws, 0, 16384, stream);

    rnn_colsum<<<dim3(1), dim3(512), 0, stream>>>(
        weight, inith, (float*)(ws + COLSUM_OFF), (float*)(ws + COLSUM1_OFF),
        (unsigned*)(ws + AFLAG_OFF));
    rnn_xproj<<<dim3(T_STEPS * 8), dim3(256), 0, stream>>>(input, weight, biasp, out);
    rnn_flags<<<dim3(T_STEPS), dim3(256), 0, stream>>>(
        out, (const float*)(ws + COLSUM_OFF), (unsigned*)(ws + AFLAG_OFF));
    rnn_cert<<<dim3(NGROUP), dim3(256), 0, stream>>>(
        weight, out, (const float*)(ws + COLSUM1_OFF),
        (const unsigned*)(ws + AFLAG_OFF), (unsigned*)(ws + CERT_OFF));
    rnn_scan<<<dim3(NGROUP * NSLICE), dim3(128), 0, stream>>>(
        weight, inith, out, ws, (const unsigned*)(ws + CERT_OFF));
}